// Round 4
// baseline (410.944 us; speedup 1.0000x reference)
//
#include <hip/hip_runtime.h>
#include <math.h>

#define NN 4096
#define DD 256
#define KK 3
#define RR 32
#define MAXNNZ 128

static constexpr float ETA    = 0.5f;
static constexpr float COEFF  = 0.03125f;   // R/(N*eps^2) = 32/(4096*0.25)
static constexpr float LN_EPSF = 1e-5f;

// workspace layout (float offsets)
#define OFF_H1   0
#define OFF_H2   (NN*DD)
#define OFF_H3   (2*NN*DD)
#define OFF_Y    (3*NN*DD)
#define OFF_P    (OFF_Y + KK*NN*RR)
#define OFF_M    (OFF_P + KK*NN*RR)
#define OFF_MINV (OFF_M + KK*RR*RR)
#define OFF_SCAL (OFF_MINV + KK*RR*RR)   // w[3], laps[3]
#define OFF_NNZ  (OFF_SCAL + 8)          // N ints
#define OFF_COLS (OFF_NNZ + NN)          // N*MAXNNZ ints
#define OFF_VALS (OFF_COLS + NN*MAXNNZ)  // N*MAXNNZ floats
#define OFF_PART (OFF_VALS + NN*MAXNNZ)  // NN/4 floats (lap_smooth partials)
#define OFF_ORTH (OFF_PART + NN/4)       // 6 floats (orth partials)
#define OFF_CTR  (OFF_ORTH + 8)          // 2 ints (gram counter, lapsm counter)

// ---------------- dispatch 1: CSR extract (blocks <NN) + orth (NN..NN+5) + prep (NN+6) ----
__global__ void k_csr_prep(const float* __restrict__ A, int* __restrict__ nnz,
                           int* __restrict__ cols, float* __restrict__ vals,
                           const float* __restrict__ hw, const float* __restrict__ ll,
                           const float* __restrict__ U,
                           float* __restrict__ ws, float* __restrict__ out) {
  int b = blockIdx.x;
  int t = threadIdx.x;
  if (b >= NN) {
    int p = b - NN;
    if (p == 6) {
      if (t == 0) {
        float m = fmaxf(fmaxf(hw[0], hw[1]), hw[2]);
        float e0 = expf(hw[0]-m), e1 = expf(hw[1]-m), e2 = expf(hw[2]-m);
        float s = e0 + e1 + e2;
        float w0 = e0/s, w1 = e1/s, w2 = e2/s;
        ws[OFF_SCAL+0] = w0; ws[OFF_SCAL+1] = w1; ws[OFF_SCAL+2] = w2;
        for (int k = 0; k < KK; ++k) {
          float x = ll[k];
          ws[OFF_SCAL+3+k] = (x > 20.f) ? x : log1pf(expf(x));
        }
        out[NN*DD + 2] = w0; out[NN*DD + 3] = w1; out[NN*DD + 4] = w2;  // w output
        ((int*)(ws + OFF_CTR))[0] = 0;   // gram counter
        ((int*)(ws + OFF_CTR))[1] = 0;   // lapsm counter
      }
      for (int idx = t; idx < KK*RR*RR; idx += 256) {
        int rr2 = idx % (RR*RR);
        ws[OFF_M + idx] = ((rr2 / RR) == (rr2 % RR)) ? 1.f : 0.f;
      }
      return;
    }
    // orth pair p: thread owns 4 cells (same col bb, rows a, a+8, a+16, a+24)
    int k = (p < 3) ? 0 : ((p < 5) ? 1 : 2);
    int l = (p < 3) ? p : ((p < 5) ? p - 2 : 2);
    int a0 = t >> 5, bb = t & 31;
    float s0 = 0.f, s1 = 0.f, s2 = 0.f, s3 = 0.f;
    for (int dd = 0; dd < DD; ++dd) {
      float ul = U[(size_t)l*DD*RR + dd*RR + bb];
      const float* uk = U + (size_t)k*DD*RR + dd*RR;
      s0 += uk[a0]      * ul;
      s1 += uk[a0 + 8]  * ul;
      s2 += uk[a0 + 16] * ul;
      s3 += uk[a0 + 24] * ul;
    }
    if (k == l && bb == a0)      s0 -= 1.f;
    if (k == l && bb == a0 + 8)  s1 -= 1.f;
    if (k == l && bb == a0 + 16) s2 -= 1.f;
    if (k == l && bb == a0 + 24) s3 -= 1.f;
    float sq = s0*s0 + s1*s1 + s2*s2 + s3*s3;
    #pragma unroll
    for (int o = 32; o > 0; o >>= 1) sq += __shfl_xor(sq, o, 64);
    __shared__ float red[4];
    if ((t & 63) == 0) red[t >> 6] = sq;
    __syncthreads();
    if (t == 0) ws[OFF_ORTH + p] = red[0] + red[1] + red[2] + red[3];
    return;
  }
  // CSR extraction; rows padded to multiple of 8 with (col=i, val=0)
  int i = b;
  __shared__ int cnt;
  if (t == 0) cnt = 0;
  __syncthreads();
  const float4* row4 = (const float4*)(A + (size_t)i * NN);
  for (int j0 = 0; j0 < NN/4; j0 += 256) {
    float4 v = row4[j0 + t];
    int jb = (j0 + t) * 4;
    if (v.x != 0.f) { int p = atomicAdd(&cnt,1); if (p<MAXNNZ){cols[i*MAXNNZ+p]=jb+0; vals[i*MAXNNZ+p]=v.x;} }
    if (v.y != 0.f) { int p = atomicAdd(&cnt,1); if (p<MAXNNZ){cols[i*MAXNNZ+p]=jb+1; vals[i*MAXNNZ+p]=v.y;} }
    if (v.z != 0.f) { int p = atomicAdd(&cnt,1); if (p<MAXNNZ){cols[i*MAXNNZ+p]=jb+2; vals[i*MAXNNZ+p]=v.z;} }
    if (v.w != 0.f) { int p = atomicAdd(&cnt,1); if (p<MAXNNZ){cols[i*MAXNNZ+p]=jb+3; vals[i*MAXNNZ+p]=v.w;} }
  }
  __syncthreads();
  int n = cnt < MAXNNZ ? cnt : MAXNNZ;
  int npad = (n + 7) & ~7;
  for (int e = n + t; e < npad; e += 256) {
    cols[i*MAXNNZ + e] = i;
    vals[i*MAXNNZ + e] = 0.f;
  }
  if (t == 0) nnz[i] = n;
}

// ---------------- sparse A @ X with fused subspace projections ----------------
__global__ void k_spmvy(const float* __restrict__ X, float* __restrict__ Hout,
                        const int* __restrict__ nnz, const int* __restrict__ cols,
                        const float* __restrict__ vals,
                        const float* __restrict__ Uo, float* __restrict__ Yo,
                        const float* __restrict__ Un, float* __restrict__ Yn) {
  int t = threadIdx.x;
  int r = t >> 6, lane = t & 63;
  int row = blockIdx.x * 4 + r;
  int d4 = lane * 4;
  int n = nnz[row];
  int npad = (n + 7) & ~7;
  const int* ci = cols + row*MAXNNZ;
  const float* vi = vals + row*MAXNNZ;
  float4 acc = {0.f, 0.f, 0.f, 0.f};
  float4 own = {0.f, 0.f, 0.f, 0.f};
  for (int e0 = 0; e0 < npad; e0 += 8) {
    int4 c0 = *(const int4*)(ci + e0);
    int4 c1 = *(const int4*)(ci + e0 + 4);
    float4 v0 = *(const float4*)(vi + e0);
    float4 v1 = *(const float4*)(vi + e0 + 4);
    float4 x0 = *(const float4*)(X + (size_t)c0.x*DD + d4);
    float4 x1 = *(const float4*)(X + (size_t)c0.y*DD + d4);
    float4 x2 = *(const float4*)(X + (size_t)c0.z*DD + d4);
    float4 x3 = *(const float4*)(X + (size_t)c0.w*DD + d4);
    float4 x4 = *(const float4*)(X + (size_t)c1.x*DD + d4);
    float4 x5 = *(const float4*)(X + (size_t)c1.y*DD + d4);
    float4 x6 = *(const float4*)(X + (size_t)c1.z*DD + d4);
    float4 x7 = *(const float4*)(X + (size_t)c1.w*DD + d4);
    if (c0.x == row) own = x0;
    if (c0.y == row) own = x1;
    if (c0.z == row) own = x2;
    if (c0.w == row) own = x3;
    if (c1.x == row) own = x4;
    if (c1.y == row) own = x5;
    if (c1.z == row) own = x6;
    if (c1.w == row) own = x7;
    acc.x += v0.x*x0.x + v0.y*x1.x + v0.z*x2.x + v0.w*x3.x + v1.x*x4.x + v1.y*x5.x + v1.z*x6.x + v1.w*x7.x;
    acc.y += v0.x*x0.y + v0.y*x1.y + v0.z*x2.y + v0.w*x3.y + v1.x*x4.y + v1.y*x5.y + v1.z*x6.y + v1.w*x7.y;
    acc.z += v0.x*x0.z + v0.y*x1.z + v0.z*x2.z + v0.w*x3.z + v1.x*x4.z + v1.y*x5.z + v1.z*x6.z + v1.w*x7.z;
    acc.w += v0.x*x0.w + v0.y*x1.w + v0.z*x2.w + v0.w*x3.w + v1.x*x4.w + v1.y*x5.w + v1.z*x6.w + v1.w*x7.w;
  }
  *(float4*)(Hout + (size_t)row*DD + d4) = acc;
  if (!Uo && !Un) return;
  __shared__ float Hs[4][2][DD];
  *(float4*)&Hs[r][0][d4] = own;
  *(float4*)&Hs[r][1][d4] = acc;
  __syncthreads();
  int c = lane & 31, h = lane >> 5;
  if (Uo) {
    float part = 0.f;
    #pragma unroll 8
    for (int d = h*128; d < h*128 + 128; ++d) part += Hs[r][0][d] * Uo[d*RR + c];
    part += __shfl_xor(part, 32, 64);
    if (h == 0) Yo[(size_t)row*RR + c] = part;
  }
  if (Un) {
    float part = 0.f;
    #pragma unroll 8
    for (int d = h*128; d < h*128 + 128; ++d) part += Hs[r][1][d] * Un[d*RR + c];
    part += __shfl_xor(part, 32, 64);
    if (h == 0) Yn[(size_t)row*RR + c] = part;
  }
}

// ---------------- dispatch 4: spmv3 (blocks <NN/4) + gram (96 blocks) + last-block GJ ----
__global__ __launch_bounds__(256) void k_spmv_gram(const float* __restrict__ X,
                        float* __restrict__ Hout,
                        const int* __restrict__ nnz, const int* __restrict__ cols,
                        const float* __restrict__ vals,
                        const float* __restrict__ Y, float* __restrict__ M,
                        float* __restrict__ Minv, int* __restrict__ ctr) {
  int t = threadIdx.x;
  if (blockIdx.x < NN/4) {
    int r = t >> 6, lane = t & 63;
    int row = blockIdx.x * 4 + r;
    int d4 = lane * 4;
    int n = nnz[row];
    int npad = (n + 7) & ~7;
    const int* ci = cols + row*MAXNNZ;
    const float* vi = vals + row*MAXNNZ;
    float4 acc = {0.f, 0.f, 0.f, 0.f};
    for (int e0 = 0; e0 < npad; e0 += 8) {
      int4 c0 = *(const int4*)(ci + e0);
      int4 c1 = *(const int4*)(ci + e0 + 4);
      float4 v0 = *(const float4*)(vi + e0);
      float4 v1 = *(const float4*)(vi + e0 + 4);
      float4 x0 = *(const float4*)(X + (size_t)c0.x*DD + d4);
      float4 x1 = *(const float4*)(X + (size_t)c0.y*DD + d4);
      float4 x2 = *(const float4*)(X + (size_t)c0.z*DD + d4);
      float4 x3 = *(const float4*)(X + (size_t)c0.w*DD + d4);
      float4 x4 = *(const float4*)(X + (size_t)c1.x*DD + d4);
      float4 x5 = *(const float4*)(X + (size_t)c1.y*DD + d4);
      float4 x6 = *(const float4*)(X + (size_t)c1.z*DD + d4);
      float4 x7 = *(const float4*)(X + (size_t)c1.w*DD + d4);
      acc.x += v0.x*x0.x + v0.y*x1.x + v0.z*x2.x + v0.w*x3.x + v1.x*x4.x + v1.y*x5.x + v1.z*x6.x + v1.w*x7.x;
      acc.y += v0.x*x0.y + v0.y*x1.y + v0.z*x2.y + v0.w*x3.y + v1.x*x4.y + v1.y*x5.y + v1.z*x6.y + v1.w*x7.y;
      acc.z += v0.x*x0.z + v0.y*x1.z + v0.z*x2.z + v0.w*x3.z + v1.x*x4.z + v1.y*x5.z + v1.z*x6.z + v1.w*x7.z;
      acc.w += v0.x*x0.w + v0.y*x1.w + v0.z*x2.w + v0.w*x3.w + v1.x*x4.w + v1.y*x5.w + v1.z*x6.w + v1.w*x7.w;
    }
    *(float4*)(Hout + (size_t)row*DD + d4) = acc;
    return;
  }
  // gram: 96 blocks, (k, chunk-of-128-rows)
  int g = blockIdx.x - NN/4;
  int k = g >> 5, chunk = g & 31;
  __shared__ float Ys[128*RR];   // 16 KB
  const float* Yk = Y + (size_t)k*NN*RR + (size_t)chunk*128*RR;
  for (int idx = t; idx < 128*RR; idx += 256) Ys[idx] = Yk[idx];
  __syncthreads();
  #pragma unroll
  for (int q = 0; q < 4; ++q) {
    int cell = t + q*256;
    int a = cell >> 5, bb = cell & 31;
    float s = 0.f;
    for (int i = 0; i < 128; ++i) s += Ys[i*RR + a] * Ys[i*RR + bb];
    atomicAdd(&M[k*RR*RR + a*RR + bb], COEFF * s);
  }
  __threadfence();
  __shared__ int amLast;
  if (t == 0) amLast = (atomicAdd(ctr, 1) == 95) ? 1 : 0;
  __syncthreads();
  if (!amLast) return;
  __threadfence();
  // Gauss-Jordan inverse for all 3 k (M is SPD, strongly diag-dominant: M ≈ I + 0.03*Gram)
  __shared__ float B[RR][2*RR];
  for (int kk2 = 0; kk2 < KK; ++kk2) {
    for (int idx = t; idx < RR*2*RR; idx += 256) {
      int r = idx >> 6, c = idx & 63;
      float mv;
      if (c < RR)
        mv = __hip_atomic_load(&M[kk2*RR*RR + r*RR + c], __ATOMIC_RELAXED, __HIP_MEMORY_SCOPE_AGENT);
      else
        mv = (c - RR == r) ? 1.f : 0.f;
      B[r][c] = mv;
    }
    __syncthreads();
    int c = t & 63, r0 = t >> 6;
    for (int j = 0; j < RR; ++j) {
      float bjc = B[j][c];
      float pinv = 1.f / B[j][j];
      float f[8];
      #pragma unroll
      for (int q = 0; q < 8; ++q) f[q] = B[r0 + 4*q][j];
      __syncthreads();
      float pb = pinv * bjc;
      #pragma unroll
      for (int q = 0; q < 8; ++q) {
        int r = r0 + 4*q;
        B[r][c] = (r == j) ? pb : (B[r][c] - f[q] * pb);
      }
      __syncthreads();
    }
    for (int idx = t; idx < RR*RR; idx += 256)
      Minv[kk2*RR*RR + (idx >> 5)*RR + (idx & 31)] = B[idx >> 5][RR + (idx & 31)];
    __syncthreads();
  }
}

// ---------------- sparse masked attention via q = Minv Y_i; P_i = Minv (sum alpha Y_j) ----
__global__ void k_attn(const float* __restrict__ Y, const float* __restrict__ Minv,
                       float* __restrict__ P, const int* __restrict__ nnz,
                       const int* __restrict__ cols) {
  int i = blockIdx.x, k = blockIdx.y;
  int t = threadIdx.x;          // 64 = one wave
  const float* Yk = Y + (size_t)k*NN*RR;
  __shared__ float Mi[RR*RR];   // Minv (symmetric)
  __shared__ float Yi[RR];
  __shared__ float qv[RR];
  __shared__ float sc[MAXNNZ];
  __shared__ float vsum[RR];
  for (int idx = t; idx < RR*RR; idx += 64) Mi[idx] = Minv[k*RR*RR + idx];
  if (t < RR) Yi[t] = Yk[(size_t)i*RR + t];
  sc[t] = -1e30f; sc[t+64] = -1e30f;
  __syncthreads();
  if (t < RR) {
    float s = 0.f;
    #pragma unroll 8
    for (int a = 0; a < RR; ++a) s += Mi[a*RR + t] * Yi[a];   // symmetric, bank-conflict-free
    qv[t] = s;
  }
  __syncthreads();
  int n = nnz[i], npad = (n + 7) & ~7;
  const int* ci = cols + i*MAXNNZ;
  for (int e = t; e < npad; e += 64) {
    const float4* yr = (const float4*)(Yk + (size_t)ci[e]*RR);
    float s = 0.f;
    #pragma unroll
    for (int qq = 0; qq < 8; ++qq) {
      float4 yv = yr[qq];
      s += yv.x*qv[4*qq] + yv.y*qv[4*qq+1] + yv.z*qv[4*qq+2] + yv.w*qv[4*qq+3];
    }
    sc[e] = (e < n) ? s : -1e30f;
  }
  __syncthreads();
  float s0 = sc[t], s1 = sc[t+64];
  float m = fmaxf(s0, s1);
  #pragma unroll
  for (int o = 32; o > 0; o >>= 1) m = fmaxf(m, __shfl_xor(m, o, 64));
  float e0v = expf(s0 - m), e1v = expf(s1 - m);
  sc[t] = e0v; sc[t+64] = e1v;
  float l = e0v + e1v;
  #pragma unroll
  for (int o = 32; o > 0; o >>= 1) l += __shfl_xor(l, o, 64);
  float linv = 1.f / l;
  __syncthreads();
  int c = t & 31, h = t >> 5;
  float acc = 0.f;
  for (int e = h; e < npad; e += 2) acc += sc[e] * Yk[(size_t)ci[e]*RR + c];
  acc += __shfl_xor(acc, 32, 64);
  if (t < RR) vsum[t] = acc * linv;
  __syncthreads();
  if (t < RR) {
    float s = 0.f;
    #pragma unroll 8
    for (int a = 0; a < RR; ++a) s += Mi[a*RR + t] * vsum[a];
    P[(size_t)k*NN*RR + (size_t)i*RR + t] = s;
  }
}

// ---------------- fused epilogue ----------------
__global__ void k_epi(const float* __restrict__ H0, const float* __restrict__ ws,
                      const float* __restrict__ U, const float* __restrict__ thr,
                      const float* __restrict__ gma, const float* __restrict__ bta,
                      float* __restrict__ out) {
  __shared__ float Us[DD][RR+1];
  __shared__ float Ps[8][KK*RR];
  int t = threadIdx.x;
  int ty = t >> 5, tx = t & 31;
  int row0 = blockIdx.x * 8;
  const float* P    = ws + OFF_P;
  const float* scal = ws + OFF_SCAL;
  for (int idx = t; idx < 8*KK*RR; idx += 256) {
    int rl = idx / (KK*RR), kr = idx % (KK*RR);
    int k = kr / RR, rr2 = kr % RR;
    Ps[rl][kr] = P[(size_t)k*NN*RR + (size_t)(row0+rl)*RR + rr2];
  }
  float lp0 = scal[3], lp1 = scal[4], lp2 = scal[5];
  float gacc[8];
  #pragma unroll
  for (int j = 0; j < 8; ++j) gacc[j] = 0.f;
  for (int k = 0; k < KK; ++k) {
    __syncthreads();
    for (int idx = t; idx < DD*RR; idx += 256) Us[idx >> 5][idx & 31] = U[(size_t)k*DD*RR + idx];
    __syncthreads();
    float wk = scal[k];
    #pragma unroll
    for (int j = 0; j < 8; ++j) {
      int d = tx + 32*j;
      float s = 0.f;
      #pragma unroll
      for (int rr2 = 0; rr2 < RR; ++rr2) s += Ps[ty][k*RR + rr2] * Us[d][rr2];
      gacc[j] += wk * s;
    }
  }
  int i = row0 + ty;
  const float* H1 = ws + OFF_H1;
  const float* H2 = ws + OFF_H2;
  const float* H3 = ws + OFF_H3;
  float v[8]; float sum = 0.f, sumsq = 0.f;
  #pragma unroll
  for (int j = 0; j < 8; ++j) {
    int d = tx + 32*j;
    size_t idx = (size_t)i*DD + d;
    float h0 = H0[idx], h1 = H1[idx], h2 = H2[idx], h3 = H3[idx];
    float lap = lp0*(h0-h1) + lp1*(h1-h2) + lp2*(h2-h3);
    float hf = h0 + ETA*gacc[j] - ETA*lap;
    float a = fabsf(hf) - thr[d];
    float sft = (a > 0.f) ? copysignf(a, hf) : 0.f;
    float x = sft + h0;
    v[j] = x; sum += x; sumsq += x*x;
  }
  #pragma unroll
  for (int o = 16; o > 0; o >>= 1) {
    sum   += __shfl_xor(sum, o, 32);
    sumsq += __shfl_xor(sumsq, o, 32);
  }
  float mu  = sum * (1.f/DD);
  float var = sumsq * (1.f/DD) - mu*mu;
  float inv = rsqrtf(var + LN_EPSF);
  #pragma unroll
  for (int j = 0; j < 8; ++j) {
    int d = tx + 32*j;
    out[(size_t)i*DD + d] = (v[j] - mu) * inv * gma[d] + bta[d];
  }
}

// ---------------- lap_smooth partials + last-block final reduce (lap + orth) ----------------
__global__ void k_lapsm_red(const float* __restrict__ Hout, const int* __restrict__ nnz,
                            const int* __restrict__ cols, const float* __restrict__ vals,
                            float* __restrict__ ws, int* __restrict__ ctr,
                            float* __restrict__ out) {
  float* partial = ws + OFF_PART;
  int t = threadIdx.x;
  int row = blockIdx.x * 4 + (t >> 6);
  int d4 = (t & 63) * 4;
  int n = nnz[row];
  int npad = (n + 7) & ~7;
  const int* ci = cols + row*MAXNNZ;
  const float* vi = vals + row*MAXNNZ;
  float4 acc = {0.f, 0.f, 0.f, 0.f};
  for (int e0 = 0; e0 < npad; e0 += 8) {
    int4 c0 = *(const int4*)(ci + e0);
    int4 c1 = *(const int4*)(ci + e0 + 4);
    float4 v0 = *(const float4*)(vi + e0);
    float4 v1 = *(const float4*)(vi + e0 + 4);
    float4 x0 = *(const float4*)(Hout + (size_t)c0.x*DD + d4);
    float4 x1 = *(const float4*)(Hout + (size_t)c0.y*DD + d4);
    float4 x2 = *(const float4*)(Hout + (size_t)c0.z*DD + d4);
    float4 x3 = *(const float4*)(Hout + (size_t)c0.w*DD + d4);
    float4 x4 = *(const float4*)(Hout + (size_t)c1.x*DD + d4);
    float4 x5 = *(const float4*)(Hout + (size_t)c1.y*DD + d4);
    float4 x6 = *(const float4*)(Hout + (size_t)c1.z*DD + d4);
    float4 x7 = *(const float4*)(Hout + (size_t)c1.w*DD + d4);
    acc.x += v0.x*x0.x + v0.y*x1.x + v0.z*x2.x + v0.w*x3.x + v1.x*x4.x + v1.y*x5.x + v1.z*x6.x + v1.w*x7.x;
    acc.y += v0.x*x0.y + v0.y*x1.y + v0.z*x2.y + v0.w*x3.y + v1.x*x4.y + v1.y*x5.y + v1.z*x6.y + v1.w*x7.y;
    acc.z += v0.x*x0.z + v0.y*x1.z + v0.z*x2.z + v0.w*x3.z + v1.x*x4.z + v1.y*x5.z + v1.z*x6.z + v1.w*x7.z;
    acc.w += v0.x*x0.w + v0.y*x1.w + v0.z*x2.w + v0.w*x3.w + v1.x*x4.w + v1.y*x5.w + v1.z*x6.w + v1.w*x7.w;
  }
  float4 hh = *(const float4*)(Hout + (size_t)row*DD + d4);
  float part = hh.x*(hh.x-acc.x) + hh.y*(hh.y-acc.y) + hh.z*(hh.z-acc.z) + hh.w*(hh.w-acc.w);
  #pragma unroll
  for (int o = 32; o > 0; o >>= 1) part += __shfl_xor(part, o, 64);
  __shared__ float red[4];
  if ((t & 63) == 0) red[t >> 6] = part;
  __syncthreads();
  if (t == 0) partial[blockIdx.x] = red[0] + red[1] + red[2] + red[3];
  __threadfence();
  __shared__ int amLast;
  if (t == 0) amLast = (atomicAdd(ctr, 1) == (NN/4 - 1)) ? 1 : 0;
  __syncthreads();
  if (!amLast) return;
  __threadfence();
  float s = 0.f;
  for (int idx = t; idx < NN/4; idx += 256)
    s += __hip_atomic_load(&partial[idx], __ATOMIC_RELAXED, __HIP_MEMORY_SCOPE_AGENT);
  #pragma unroll
  for (int o = 32; o > 0; o >>= 1) s += __shfl_xor(s, o, 64);
  if ((t & 63) == 0) red[t >> 6] = s;
  __syncthreads();
  if (t == 0) {
    out[1] = red[0] + red[1] + red[2] + red[3];   // lap_smooth
    const float* op = ws + OFF_ORTH;
    float orth = 0.f;
    for (int p = 0; p < 6; ++p)
      orth += __hip_atomic_load((float*)&op[p], __ATOMIC_RELAXED, __HIP_MEMORY_SCOPE_AGENT);
    out[0] = orth;                                 // orth_loss
  }
}

extern "C" void kernel_launch(void* const* d_in, const int* in_sizes, int n_in,
                              void* d_out, int out_size, void* d_ws, size_t ws_size,
                              hipStream_t stream) {
  const float* H   = (const float*)d_in[0];
  const float* A   = (const float*)d_in[1];
  // d_in[2] (adj_mask) and d_in[3] (L) are never read: mask == (A != 0), L == I - A
  const float* U   = (const float*)d_in[4];
  const float* ll  = (const float*)d_in[5];
  const float* hw  = (const float*)d_in[6];
  const float* thr = (const float*)d_in[7];
  const float* gma = (const float*)d_in[8];
  const float* bta = (const float*)d_in[9];
  float* out = (float*)d_out;
  float* ws  = (float*)d_ws;
  int* nnz   = (int*)(ws + OFF_NNZ);
  int* cols  = (int*)(ws + OFF_COLS);
  float* vals = ws + OFF_VALS;
  int* ctr   = (int*)(ws + OFF_CTR);
  float* Y = ws + OFF_Y;

  // 1: CSR + orth partials + scalars/M-init/counter-zero
  k_csr_prep<<<NN + 7, 256, 0, stream>>>(A, nnz, cols, vals, hw, ll, U, ws, out);
  // 2: H1 = A@H, Y0 = H@U0, Y1 = H1@U1
  k_spmvy<<<NN/4, 256, 0, stream>>>(H, ws + OFF_H1, nnz, cols, vals,
                                    U, Y, U + (size_t)DD*RR, Y + (size_t)NN*RR);
  // 3: H2 = A@H1, Y2 = H2@U2
  k_spmvy<<<NN/4, 256, 0, stream>>>(ws + OFF_H1, ws + OFF_H2, nnz, cols, vals,
                                    nullptr, nullptr, U + (size_t)2*DD*RR, Y + (size_t)2*NN*RR);
  // 4: H3 = A@H2 + gram(M += c*Y^T Y) + last-block Gauss-Jordan inverse
  k_spmv_gram<<<NN/4 + 96, 256, 0, stream>>>(ws + OFF_H2, ws + OFF_H3, nnz, cols, vals,
                                             Y, ws + OFF_M, ws + OFF_MINV, ctr);
  // 5: attention (W never materialized: scores = (Minv Y_i)·Y_j, P_i = Minv Σ α Y_j)
  dim3 gattn(NN, KK);
  k_attn<<<gattn, 64, 0, stream>>>(Y, ws + OFF_MINV, ws + OFF_P, nnz, cols);
  // 6: epilogue
  k_epi<<<NN/8, 256, 0, stream>>>(H, ws, U, thr, gma, bta, out);
  // 7: lap_smooth + final reduce (lap + orth)
  k_lapsm_red<<<NN/4, 256, 0, stream>>>(out, nnz, cols, vals, ws, ctr + 1, out + NN*DD);
  // out layout: [H_out (NN*DD)] [orth_loss] [lap_smooth] [w0 w1 w2]
}

// Round 5
// 293.085 us; speedup vs baseline: 1.4021x; 1.4021x over previous
//
#include <hip/hip_runtime.h>
#include <math.h>

#define NN 4096
#define DD 256
#define KK 3
#define RR 32
#define MAXNNZ 128

static constexpr float ETA    = 0.5f;
static constexpr float COEFF  = 0.03125f;   // R/(N*eps^2) = 32/(4096*0.25)
static constexpr float LN_EPSF = 1e-5f;

// workspace layout (float offsets)
#define OFF_H1   0
#define OFF_H2   (NN*DD)
#define OFF_H3   (2*NN*DD)
#define OFF_Y    (3*NN*DD)
#define OFF_P    (OFF_Y + KK*NN*RR)
#define OFF_M    (OFF_P + KK*NN*RR)
#define OFF_MINV (OFF_M + KK*RR*RR)
#define OFF_SCAL (OFF_MINV + KK*RR*RR)   // w[3], laps[3]
#define OFF_NNZ  (OFF_SCAL + 8)          // N ints
#define OFF_COLS (OFF_NNZ + NN)          // N*MAXNNZ ints
#define OFF_VALS (OFF_COLS + NN*MAXNNZ)  // N*MAXNNZ floats
#define OFF_PART (OFF_VALS + NN*MAXNNZ)  // NN/4 floats (lap_smooth partials)
#define OFF_ORTH (OFF_PART + NN/4)       // 6 floats (orth partials)

// ---------------- dispatch 1: CSR extract (blocks <NN) + orth (NN..NN+5) + prep (NN+6) ----
// NOTE: no device-scope fences anywhere — R4 showed __threadfence's L2 writeback/invalidate
// destroys cache residency for concurrent gather blocks (k_lapsm_red 94us @ 1.6% HBM).
// Dispatch boundaries provide all the ordering we need.
__global__ void k_csr_prep(const float* __restrict__ A, int* __restrict__ nnz,
                           int* __restrict__ cols, float* __restrict__ vals,
                           const float* __restrict__ hw, const float* __restrict__ ll,
                           const float* __restrict__ U,
                           float* __restrict__ ws, float* __restrict__ out) {
  int b = blockIdx.x;
  int t = threadIdx.x;
  if (b >= NN) {
    int p = b - NN;
    if (p == 6) {
      if (t == 0) {
        float m = fmaxf(fmaxf(hw[0], hw[1]), hw[2]);
        float e0 = expf(hw[0]-m), e1 = expf(hw[1]-m), e2 = expf(hw[2]-m);
        float s = e0 + e1 + e2;
        float w0 = e0/s, w1 = e1/s, w2 = e2/s;
        ws[OFF_SCAL+0] = w0; ws[OFF_SCAL+1] = w1; ws[OFF_SCAL+2] = w2;
        for (int k = 0; k < KK; ++k) {
          float x = ll[k];
          ws[OFF_SCAL+3+k] = (x > 20.f) ? x : log1pf(expf(x));
        }
        out[NN*DD + 2] = w0; out[NN*DD + 3] = w1; out[NN*DD + 4] = w2;  // w output
      }
      for (int idx = t; idx < KK*RR*RR; idx += 256) {
        int rr2 = idx % (RR*RR);
        ws[OFF_M + idx] = ((rr2 / RR) == (rr2 % RR)) ? 1.f : 0.f;
      }
      return;
    }
    // orth pair p: thread owns 4 cells (same col bb, rows a0, a0+8, a0+16, a0+24)
    int k = (p < 3) ? 0 : ((p < 5) ? 1 : 2);
    int l = (p < 3) ? p : ((p < 5) ? p - 2 : 2);
    int a0 = t >> 5, bb = t & 31;
    float s0 = 0.f, s1 = 0.f, s2 = 0.f, s3 = 0.f;
    for (int dd = 0; dd < DD; ++dd) {
      float ul = U[(size_t)l*DD*RR + dd*RR + bb];
      const float* uk = U + (size_t)k*DD*RR + dd*RR;
      s0 += uk[a0]      * ul;
      s1 += uk[a0 + 8]  * ul;
      s2 += uk[a0 + 16] * ul;
      s3 += uk[a0 + 24] * ul;
    }
    if (k == l && bb == a0)      s0 -= 1.f;
    if (k == l && bb == a0 + 8)  s1 -= 1.f;
    if (k == l && bb == a0 + 16) s2 -= 1.f;
    if (k == l && bb == a0 + 24) s3 -= 1.f;
    float sq = s0*s0 + s1*s1 + s2*s2 + s3*s3;
    #pragma unroll
    for (int o = 32; o > 0; o >>= 1) sq += __shfl_xor(sq, o, 64);
    __shared__ float red[4];
    if ((t & 63) == 0) red[t >> 6] = sq;
    __syncthreads();
    if (t == 0) ws[OFF_ORTH + p] = red[0] + red[1] + red[2] + red[3];
    return;
  }
  // CSR extraction; rows padded to multiple of 8 with (col=i, val=0)
  int i = b;
  __shared__ int cnt;
  if (t == 0) cnt = 0;
  __syncthreads();
  const float4* row4 = (const float4*)(A + (size_t)i * NN);
  for (int j0 = 0; j0 < NN/4; j0 += 256) {
    float4 v = row4[j0 + t];
    int jb = (j0 + t) * 4;
    if (v.x != 0.f) { int p = atomicAdd(&cnt,1); if (p<MAXNNZ){cols[i*MAXNNZ+p]=jb+0; vals[i*MAXNNZ+p]=v.x;} }
    if (v.y != 0.f) { int p = atomicAdd(&cnt,1); if (p<MAXNNZ){cols[i*MAXNNZ+p]=jb+1; vals[i*MAXNNZ+p]=v.y;} }
    if (v.z != 0.f) { int p = atomicAdd(&cnt,1); if (p<MAXNNZ){cols[i*MAXNNZ+p]=jb+2; vals[i*MAXNNZ+p]=v.z;} }
    if (v.w != 0.f) { int p = atomicAdd(&cnt,1); if (p<MAXNNZ){cols[i*MAXNNZ+p]=jb+3; vals[i*MAXNNZ+p]=v.w;} }
  }
  __syncthreads();
  int n = cnt < MAXNNZ ? cnt : MAXNNZ;
  int npad = (n + 7) & ~7;
  for (int e = n + t; e < npad; e += 256) {
    cols[i*MAXNNZ + e] = i;
    vals[i*MAXNNZ + e] = 0.f;
  }
  if (t == 0) nnz[i] = n;
}

// ---------------- sparse A @ X with optional fused subspace projections ----------------
__global__ void k_spmvy(const float* __restrict__ X, float* __restrict__ Hout,
                        const int* __restrict__ nnz, const int* __restrict__ cols,
                        const float* __restrict__ vals,
                        const float* __restrict__ Uo, float* __restrict__ Yo,
                        const float* __restrict__ Un, float* __restrict__ Yn) {
  int t = threadIdx.x;
  int r = t >> 6, lane = t & 63;
  int row = blockIdx.x * 4 + r;
  int d4 = lane * 4;
  int n = nnz[row];
  int npad = (n + 7) & ~7;
  const int* ci = cols + row*MAXNNZ;
  const float* vi = vals + row*MAXNNZ;
  float4 acc = {0.f, 0.f, 0.f, 0.f};
  float4 own = {0.f, 0.f, 0.f, 0.f};
  for (int e0 = 0; e0 < npad; e0 += 8) {
    int4 c0 = *(const int4*)(ci + e0);
    int4 c1 = *(const int4*)(ci + e0 + 4);
    float4 v0 = *(const float4*)(vi + e0);
    float4 v1 = *(const float4*)(vi + e0 + 4);
    float4 x0 = *(const float4*)(X + (size_t)c0.x*DD + d4);
    float4 x1 = *(const float4*)(X + (size_t)c0.y*DD + d4);
    float4 x2 = *(const float4*)(X + (size_t)c0.z*DD + d4);
    float4 x3 = *(const float4*)(X + (size_t)c0.w*DD + d4);
    float4 x4 = *(const float4*)(X + (size_t)c1.x*DD + d4);
    float4 x5 = *(const float4*)(X + (size_t)c1.y*DD + d4);
    float4 x6 = *(const float4*)(X + (size_t)c1.z*DD + d4);
    float4 x7 = *(const float4*)(X + (size_t)c1.w*DD + d4);
    if (c0.x == row) own = x0;
    if (c0.y == row) own = x1;
    if (c0.z == row) own = x2;
    if (c0.w == row) own = x3;
    if (c1.x == row) own = x4;
    if (c1.y == row) own = x5;
    if (c1.z == row) own = x6;
    if (c1.w == row) own = x7;
    acc.x += v0.x*x0.x + v0.y*x1.x + v0.z*x2.x + v0.w*x3.x + v1.x*x4.x + v1.y*x5.x + v1.z*x6.x + v1.w*x7.x;
    acc.y += v0.x*x0.y + v0.y*x1.y + v0.z*x2.y + v0.w*x3.y + v1.x*x4.y + v1.y*x5.y + v1.z*x6.y + v1.w*x7.y;
    acc.z += v0.x*x0.z + v0.y*x1.z + v0.z*x2.z + v0.w*x3.z + v1.x*x4.z + v1.y*x5.z + v1.z*x6.z + v1.w*x7.z;
    acc.w += v0.x*x0.w + v0.y*x1.w + v0.z*x2.w + v0.w*x3.w + v1.x*x4.w + v1.y*x5.w + v1.z*x6.w + v1.w*x7.w;
  }
  *(float4*)(Hout + (size_t)row*DD + d4) = acc;
  if (!Uo && !Un) return;
  __shared__ float Hs[4][2][DD];
  *(float4*)&Hs[r][0][d4] = own;
  *(float4*)&Hs[r][1][d4] = acc;
  __syncthreads();
  int c = lane & 31, h = lane >> 5;
  if (Uo) {
    float part = 0.f;
    #pragma unroll 8
    for (int d = h*128; d < h*128 + 128; ++d) part += Hs[r][0][d] * Uo[d*RR + c];
    part += __shfl_xor(part, 32, 64);
    if (h == 0) Yo[(size_t)row*RR + c] = part;
  }
  if (Un) {
    float part = 0.f;
    #pragma unroll 8
    for (int d = h*128; d < h*128 + 128; ++d) part += Hs[r][1][d] * Un[d*RR + c];
    part += __shfl_xor(part, 32, 64);
    if (h == 0) Yn[(size_t)row*RR + c] = part;
  }
}

// ---------------- M_k += coeff * Y^T Y (M pre-inited to I) ----------------
__global__ __launch_bounds__(1024) void k_gram(const float* __restrict__ Y, float* __restrict__ M) {
  int k = blockIdx.y;
  __shared__ float Ys[128*RR];
  int t = threadIdx.x;
  const float* Yk = Y + (size_t)k*NN*RR + (size_t)blockIdx.x*128*RR;
  for (int idx = t; idx < 128*RR; idx += 1024) Ys[idx] = Yk[idx];
  __syncthreads();
  int a = t >> 5, b = t & 31;
  float s = 0.f;
  for (int i = 0; i < 128; ++i) s += Ys[i*RR + a] * Ys[i*RR + b];
  atomicAdd(&M[k*RR*RR + a*RR + b], COEFF * s);
}

// ---------------- 32x32 inverse via Gauss-Jordan (M SPD, strongly diag-dominant) ----------
__global__ __launch_bounds__(256) void k_gj(const float* __restrict__ M, float* __restrict__ Minv) {
  int k = blockIdx.x;
  __shared__ float B[RR][2*RR];   // augmented [M | I]
  int t = threadIdx.x;
  for (int idx = t; idx < RR*2*RR; idx += 256) {
    int r = idx >> 6, c = idx & 63;
    B[r][c] = (c < RR) ? M[k*RR*RR + r*RR + c] : ((c - RR == r) ? 1.f : 0.f);
  }
  __syncthreads();
  int c = t & 63, r0 = t >> 6;
  for (int j = 0; j < RR; ++j) {
    float bjc = B[j][c];
    float pinv = 1.f / B[j][j];
    float f[8];
    #pragma unroll
    for (int q = 0; q < 8; ++q) f[q] = B[r0 + 4*q][j];
    __syncthreads();
    float pb = pinv * bjc;
    #pragma unroll
    for (int q = 0; q < 8; ++q) {
      int r = r0 + 4*q;
      B[r][c] = (r == j) ? pb : (B[r][c] - f[q] * pb);
    }
    __syncthreads();
  }
  for (int idx = t; idx < RR*RR; idx += 256)
    Minv[k*RR*RR + (idx >> 5)*RR + (idx & 31)] = B[idx >> 5][RR + (idx & 31)];
}

// ---------------- sparse masked attention via q = Minv Y_i; P_i = Minv (sum alpha Y_j) ----
__global__ void k_attn(const float* __restrict__ Y, const float* __restrict__ Minv,
                       float* __restrict__ P, const int* __restrict__ nnz,
                       const int* __restrict__ cols) {
  int i = blockIdx.x, k = blockIdx.y;
  int t = threadIdx.x;          // 64 = one wave
  const float* Yk = Y + (size_t)k*NN*RR;
  __shared__ float Mi[RR*RR];   // Minv (symmetric)
  __shared__ float Yi[RR];
  __shared__ float qv[RR];
  __shared__ float sc[MAXNNZ];
  __shared__ float vsum[RR];
  for (int idx = t; idx < RR*RR; idx += 64) Mi[idx] = Minv[k*RR*RR + idx];
  if (t < RR) Yi[t] = Yk[(size_t)i*RR + t];
  sc[t] = -1e30f; sc[t+64] = -1e30f;
  __syncthreads();
  if (t < RR) {
    float s = 0.f;
    #pragma unroll 8
    for (int a = 0; a < RR; ++a) s += Mi[a*RR + t] * Yi[a];   // symmetric: col t == row t
    qv[t] = s;
  }
  __syncthreads();
  int n = nnz[i], npad = (n + 7) & ~7;
  const int* ci = cols + i*MAXNNZ;
  for (int e = t; e < npad; e += 64) {
    const float4* yr = (const float4*)(Yk + (size_t)ci[e]*RR);
    float s = 0.f;
    #pragma unroll
    for (int qq = 0; qq < 8; ++qq) {
      float4 yv = yr[qq];
      s += yv.x*qv[4*qq] + yv.y*qv[4*qq+1] + yv.z*qv[4*qq+2] + yv.w*qv[4*qq+3];
    }
    sc[e] = (e < n) ? s : -1e30f;
  }
  __syncthreads();
  float s0 = sc[t], s1 = sc[t+64];
  float m = fmaxf(s0, s1);
  #pragma unroll
  for (int o = 32; o > 0; o >>= 1) m = fmaxf(m, __shfl_xor(m, o, 64));
  float e0v = expf(s0 - m), e1v = expf(s1 - m);
  sc[t] = e0v; sc[t+64] = e1v;
  float l = e0v + e1v;
  #pragma unroll
  for (int o = 32; o > 0; o >>= 1) l += __shfl_xor(l, o, 64);
  float linv = 1.f / l;
  __syncthreads();
  int c = t & 31, h = t >> 5;
  float acc = 0.f;
  for (int e = h; e < npad; e += 2) acc += sc[e] * Yk[(size_t)ci[e]*RR + c];
  acc += __shfl_xor(acc, 32, 64);
  if (t < RR) vsum[t] = acc * linv;
  __syncthreads();
  if (t < RR) {
    float s = 0.f;
    #pragma unroll 8
    for (int a = 0; a < RR; ++a) s += Mi[a*RR + t] * vsum[a];
    P[(size_t)k*NN*RR + (size_t)i*RR + t] = s;
  }
}

// ---------------- fused epilogue ----------------
__global__ void k_epi(const float* __restrict__ H0, const float* __restrict__ ws,
                      const float* __restrict__ U, const float* __restrict__ thr,
                      const float* __restrict__ gma, const float* __restrict__ bta,
                      float* __restrict__ out) {
  __shared__ float Us[DD][RR+1];
  __shared__ float Ps[8][KK*RR];
  int t = threadIdx.x;
  int ty = t >> 5, tx = t & 31;
  int row0 = blockIdx.x * 8;
  const float* P    = ws + OFF_P;
  const float* scal = ws + OFF_SCAL;
  for (int idx = t; idx < 8*KK*RR; idx += 256) {
    int rl = idx / (KK*RR), kr = idx % (KK*RR);
    int k = kr / RR, rr2 = kr % RR;
    Ps[rl][kr] = P[(size_t)k*NN*RR + (size_t)(row0+rl)*RR + rr2];
  }
  float lp0 = scal[3], lp1 = scal[4], lp2 = scal[5];
  float gacc[8];
  #pragma unroll
  for (int j = 0; j < 8; ++j) gacc[j] = 0.f;
  for (int k = 0; k < KK; ++k) {
    __syncthreads();
    for (int idx = t; idx < DD*RR; idx += 256) Us[idx >> 5][idx & 31] = U[(size_t)k*DD*RR + idx];
    __syncthreads();
    float wk = scal[k];
    #pragma unroll
    for (int j = 0; j < 8; ++j) {
      int d = tx + 32*j;
      float s = 0.f;
      #pragma unroll
      for (int rr2 = 0; rr2 < RR; ++rr2) s += Ps[ty][k*RR + rr2] * Us[d][rr2];
      gacc[j] += wk * s;
    }
  }
  int i = row0 + ty;
  const float* H1 = ws + OFF_H1;
  const float* H2 = ws + OFF_H2;
  const float* H3 = ws + OFF_H3;
  float v[8]; float sum = 0.f, sumsq = 0.f;
  #pragma unroll
  for (int j = 0; j < 8; ++j) {
    int d = tx + 32*j;
    size_t idx = (size_t)i*DD + d;
    float h0 = H0[idx], h1 = H1[idx], h2 = H2[idx], h3 = H3[idx];
    float lap = lp0*(h0-h1) + lp1*(h1-h2) + lp2*(h2-h3);
    float hf = h0 + ETA*gacc[j] - ETA*lap;
    float a = fabsf(hf) - thr[d];
    float sft = (a > 0.f) ? copysignf(a, hf) : 0.f;
    float x = sft + h0;
    v[j] = x; sum += x; sumsq += x*x;
  }
  #pragma unroll
  for (int o = 16; o > 0; o >>= 1) {
    sum   += __shfl_xor(sum, o, 32);
    sumsq += __shfl_xor(sumsq, o, 32);
  }
  float mu  = sum * (1.f/DD);
  float var = sumsq * (1.f/DD) - mu*mu;
  float inv = rsqrtf(var + LN_EPSF);
  #pragma unroll
  for (int j = 0; j < 8; ++j) {
    int d = tx + 32*j;
    out[(size_t)i*DD + d] = (v[j] - mu) * inv * gma[d] + bta[d];
  }
}

// ---------------- lap_smooth partials (no fences, no atomics) ----------------
__global__ void k_lapsm(const float* __restrict__ Hout, const int* __restrict__ nnz,
                        const int* __restrict__ cols, const float* __restrict__ vals,
                        float* __restrict__ partial) {
  int t = threadIdx.x;
  int row = blockIdx.x * 4 + (t >> 6);
  int d4 = (t & 63) * 4;
  int n = nnz[row];
  int npad = (n + 7) & ~7;
  const int* ci = cols + row*MAXNNZ;
  const float* vi = vals + row*MAXNNZ;
  float4 acc = {0.f, 0.f, 0.f, 0.f};
  for (int e0 = 0; e0 < npad; e0 += 8) {
    int4 c0 = *(const int4*)(ci + e0);
    int4 c1 = *(const int4*)(ci + e0 + 4);
    float4 v0 = *(const float4*)(vi + e0);
    float4 v1 = *(const float4*)(vi + e0 + 4);
    float4 x0 = *(const float4*)(Hout + (size_t)c0.x*DD + d4);
    float4 x1 = *(const float4*)(Hout + (size_t)c0.y*DD + d4);
    float4 x2 = *(const float4*)(Hout + (size_t)c0.z*DD + d4);
    float4 x3 = *(const float4*)(Hout + (size_t)c0.w*DD + d4);
    float4 x4 = *(const float4*)(Hout + (size_t)c1.x*DD + d4);
    float4 x5 = *(const float4*)(Hout + (size_t)c1.y*DD + d4);
    float4 x6 = *(const float4*)(Hout + (size_t)c1.z*DD + d4);
    float4 x7 = *(const float4*)(Hout + (size_t)c1.w*DD + d4);
    acc.x += v0.x*x0.x + v0.y*x1.x + v0.z*x2.x + v0.w*x3.x + v1.x*x4.x + v1.y*x5.x + v1.z*x6.x + v1.w*x7.x;
    acc.y += v0.x*x0.y + v0.y*x1.y + v0.z*x2.y + v0.w*x3.y + v1.x*x4.y + v1.y*x5.y + v1.z*x6.y + v1.w*x7.y;
    acc.z += v0.x*x0.z + v0.y*x1.z + v0.z*x2.z + v0.w*x3.z + v1.x*x4.z + v1.y*x5.z + v1.z*x6.z + v1.w*x7.z;
    acc.w += v0.x*x0.w + v0.y*x1.w + v0.z*x2.w + v0.w*x3.w + v1.x*x4.w + v1.y*x5.w + v1.z*x6.w + v1.w*x7.w;
  }
  float4 h = *(const float4*)(Hout + (size_t)row*DD + d4);
  float part = h.x*(h.x-acc.x) + h.y*(h.y-acc.y) + h.z*(h.z-acc.z) + h.w*(h.w-acc.w);
  #pragma unroll
  for (int o = 32; o > 0; o >>= 1) part += __shfl_xor(part, o, 64);
  __shared__ float red[4];
  if ((t & 63) == 0) red[t >> 6] = part;
  __syncthreads();
  if (t == 0) partial[blockIdx.x] = red[0] + red[1] + red[2] + red[3];
}

// ---------------- final reduce: lap_smooth + orth_loss ----------------
__global__ void k_red(const float* __restrict__ ws, float* __restrict__ out) {
  const float* partial = ws + OFF_PART;
  int t = threadIdx.x;  // 256 threads, 1024 partials
  float4 p = *(const float4*)(partial + t*4);
  float s = p.x + p.y + p.z + p.w;
  #pragma unroll
  for (int o = 32; o > 0; o >>= 1) s += __shfl_xor(s, o, 64);
  __shared__ float red[4];
  if ((t & 63) == 0) red[t >> 6] = s;
  __syncthreads();
  if (t == 0) {
    out[1] = red[0] + red[1] + red[2] + red[3];   // lap_smooth
    const float* op = ws + OFF_ORTH;
    out[0] = op[0] + op[1] + op[2] + op[3] + op[4] + op[5];  // orth_loss
  }
}

extern "C" void kernel_launch(void* const* d_in, const int* in_sizes, int n_in,
                              void* d_out, int out_size, void* d_ws, size_t ws_size,
                              hipStream_t stream) {
  const float* H   = (const float*)d_in[0];
  const float* A   = (const float*)d_in[1];
  // d_in[2] (adj_mask) and d_in[3] (L) are never read: mask == (A != 0), L == I - A
  const float* U   = (const float*)d_in[4];
  const float* ll  = (const float*)d_in[5];
  const float* hw  = (const float*)d_in[6];
  const float* thr = (const float*)d_in[7];
  const float* gma = (const float*)d_in[8];
  const float* bta = (const float*)d_in[9];
  float* out = (float*)d_out;
  float* ws  = (float*)d_ws;
  int* nnz   = (int*)(ws + OFF_NNZ);
  int* cols  = (int*)(ws + OFF_COLS);
  float* vals = ws + OFF_VALS;
  float* Y = ws + OFF_Y;

  // 1: CSR + orth partials + scalars/M-init
  k_csr_prep<<<NN + 7, 256, 0, stream>>>(A, nnz, cols, vals, hw, ll, U, ws, out);
  // 2: H1 = A@H, Y0 = H@U0, Y1 = H1@U1
  k_spmvy<<<NN/4, 256, 0, stream>>>(H, ws + OFF_H1, nnz, cols, vals,
                                    U, Y, U + (size_t)DD*RR, Y + (size_t)NN*RR);
  // 3: H2 = A@H1, Y2 = H2@U2
  k_spmvy<<<NN/4, 256, 0, stream>>>(ws + OFF_H1, ws + OFF_H2, nnz, cols, vals,
                                    nullptr, nullptr, U + (size_t)2*DD*RR, Y + (size_t)2*NN*RR);
  // 4: H3 = A@H2
  k_spmvy<<<NN/4, 256, 0, stream>>>(ws + OFF_H2, ws + OFF_H3, nnz, cols, vals,
                                    nullptr, nullptr, nullptr, nullptr);
  // 5: M += coeff * Y^T Y
  dim3 g32(NN/128, KK);
  k_gram<<<g32, 1024, 0, stream>>>(Y, ws + OFF_M);
  // 6: Minv = M^{-1} (Gauss-Jordan, 3 tiny blocks)
  k_gj<<<KK, 256, 0, stream>>>(ws + OFF_M, ws + OFF_MINV);
  // 7: attention (W never materialized: scores = (Minv Y_i)·Y_j, P_i = Minv Σ α Y_j)
  dim3 gattn(NN, KK);
  k_attn<<<gattn, 64, 0, stream>>>(Y, ws + OFF_MINV, ws + OFF_P, nnz, cols);
  // 8: epilogue
  k_epi<<<NN/8, 256, 0, stream>>>(H, ws, U, thr, gma, bta, out);
  // 9: lap_smooth partials
  k_lapsm<<<NN/4, 256, 0, stream>>>(out, nnz, cols, vals, ws + OFF_PART);
  // 10: final scalar reduce
  k_red<<<1, 256, 0, stream>>>(ws, out + NN*DD);
  // out layout: [H_out (NN*DD)] [orth_loss] [lap_smooth] [w0 w1 w2]
}